// Round 5
// baseline (590.487 us; speedup 1.0000x reference)
//
#include <hip/hip_runtime.h>
#include <math.h>

#define NN 50000
#define NE 1200000
#define FIN 128
#define FE 32
#define FE4 (FE / 4)
#define H 78
#define HP 80
#define ETOT (NE + NN)
#define NG (HP / 4)          // 20 float4 groups per node row

#define SCAN_B 256
#define SCAN_C 4
#define SCAN_TILE (SCAN_B * SCAN_C)                 // 1024
#define NBLK ((NN + SCAN_TILE - 1) / SCAN_TILE)     // 49

// ---------------- dense node GEMM with fused attention-score epilogue ----------------
template<int K, int LDA>
__global__ void gemm_node(const float* __restrict__ A, const float* __restrict__ W,
                          const float* __restrict__ as, const float* __restrict__ ad,
                          float* __restrict__ C, float* __restrict__ asv,
                          float* __restrict__ adv) {
  int n = blockIdx.x * blockDim.x + threadIdx.x;
  if (n >= NN) return;
  const float* a = A + (size_t)n * LDA;
  float acc[H];
#pragma unroll
  for (int j = 0; j < H; ++j) acc[j] = 0.f;
  int k = 0;
  for (; k + 4 <= K; k += 4) {
    float4 av = *reinterpret_cast<const float4*>(a + k);
    const float* w0 = W + (size_t)k * H;
#pragma unroll
    for (int j = 0; j < H; ++j) acc[j] += av.x * w0[j];
#pragma unroll
    for (int j = 0; j < H; ++j) acc[j] += av.y * w0[H + j];
#pragma unroll
    for (int j = 0; j < H; ++j) acc[j] += av.z * w0[2 * H + j];
#pragma unroll
    for (int j = 0; j < H; ++j) acc[j] += av.w * w0[3 * H + j];
  }
  for (; k < K; ++k) {
    float av = a[k];
    const float* w0 = W + (size_t)k * H;
#pragma unroll
    for (int j = 0; j < H; ++j) acc[j] += av * w0[j];
  }
  float* c = C + (size_t)n * HP;
#pragma unroll
  for (int j = 0; j < H; ++j) c[j] = acc[j];
  c[H] = 0.f;
  c[H + 1] = 0.f;
  float sa = 0.f, sd = 0.f;
#pragma unroll
  for (int j = 0; j < H; ++j) {
    sa += acc[j] * as[j];
    sd += acc[j] * ad[j];
  }
  asv[n] = sa;
  adv[n] = sd;
}

// ---------------- CSR build ----------------
__global__ void zero_deg(int* __restrict__ deg) {
  int n = blockIdx.x * blockDim.x + threadIdx.x;
  if (n < NN) deg[n] = 0;
}

__global__ void deg_count(const int* __restrict__ ei, int* __restrict__ deg) {
  int i = blockIdx.x * blockDim.x + threadIdx.x;
  if (i >= ETOT) return;
  int dst = (i < NE) ? ei[NE + i] : (i - NE);
  atomicAdd(deg + dst, 1);
}

__global__ void scan1(const int* __restrict__ deg, int* __restrict__ bsum) {
  __shared__ int sh[SCAN_B];
  int b = blockIdx.x, t = threadIdx.x;
  int base = b * SCAN_TILE + t * SCAN_C;
  int s = 0;
#pragma unroll
  for (int k = 0; k < SCAN_C; ++k) {
    int i = base + k;
    if (i < NN) s += deg[i];
  }
  sh[t] = s;
  __syncthreads();
  for (int off = SCAN_B / 2; off > 0; off >>= 1) {
    if (t < off) sh[t] += sh[t + off];
    __syncthreads();
  }
  if (t == 0) bsum[b] = sh[0];
}

__global__ void scan2(const int* __restrict__ bsum, int* __restrict__ boff) {
  __shared__ int sh[64];
  int t = threadIdx.x;
  sh[t] = (t < NBLK) ? bsum[t] : 0;
  __syncthreads();
  for (int off = 1; off < 64; off <<= 1) {
    int v = (t >= off) ? sh[t - off] : 0;
    __syncthreads();
    sh[t] += v;
    __syncthreads();
  }
  if (t < NBLK) boff[t] = (t == 0) ? 0 : sh[t - 1];
}

__global__ void scan3(const int* __restrict__ deg, const int* __restrict__ boff,
                      int* __restrict__ rowptr, int* __restrict__ cursor) {
  __shared__ int sh[SCAN_B];
  int b = blockIdx.x, t = threadIdx.x;
  int base = b * SCAN_TILE + t * SCAN_C;
  int v[SCAN_C];
  int s = 0;
#pragma unroll
  for (int k = 0; k < SCAN_C; ++k) {
    int i = base + k;
    v[k] = (i < NN) ? deg[i] : 0;
    s += v[k];
  }
  sh[t] = s;
  __syncthreads();
  for (int off = 1; off < SCAN_B; off <<= 1) {
    int u = (t >= off) ? sh[t - off] : 0;
    __syncthreads();
    sh[t] += u;
    __syncthreads();
  }
  int run = boff[b] + ((t == 0) ? 0 : sh[t - 1]);
#pragma unroll
  for (int k = 0; k < SCAN_C; ++k) {
    int i = base + k;
    if (i < NN) {
      rowptr[i] = run;
      cursor[i] = run;
      run += v[k];
    }
  }
  if (b == 0 && t == 0) rowptr[NN] = ETOT;
}

__global__ void csr_fill(const int* __restrict__ ei, int* __restrict__ cursor,
                         int* __restrict__ srcs) {
  int i = blockIdx.x * blockDim.x + threadIdx.x;
  if (i >= ETOT) return;
  int src, dst;
  if (i < NE) { src = ei[i]; dst = ei[NE + i]; }
  else { src = dst = i - NE; }
  int pos = atomicAdd(cursor + dst, 1);
  srcs[pos] = src;
}

// ---------------- per-destination ONLINE softmax (1 random-gather pass) ----------------
__global__ void softmax_csr(const int* __restrict__ rowptr, const int* __restrict__ srcs,
                            const float* __restrict__ asv, const float* __restrict__ adv,
                            float* __restrict__ aw) {
  int n = blockIdx.x * blockDim.x + threadIdx.x;
  if (n >= NN) return;
  int r0 = rowptr[n], r1 = rowptr[n + 1];
  float advn = adv[n];
  float m = -INFINITY, s = 0.f;
  for (int p = r0; p < r1; ++p) {
    float e = asv[srcs[p]] + advn;
    e = e > 0.f ? e : 0.2f * e;
    aw[p] = e;
    if (e > m) {
      s = s * __expf(m - e);   // exp(-inf)=0 handles first iteration
      m = e;
    }
    s += __expf(e - m);
  }
  float inv = 1.f / (s + 1e-16f);
  for (int p = r0; p < r1; ++p) aw[p] = __expf(aw[p] - m) * inv;
}

// ---------------- gather-based aggregation; bias (+optional relu) fused ----------------
template<int RELU>
__global__ void agg_csr(const int* __restrict__ rowptr, const int* __restrict__ srcs,
                        const float* __restrict__ aw, const float* __restrict__ h,
                        const float* __restrict__ biasp, float* __restrict__ outp) {
  int t = blockIdx.x * blockDim.x + threadIdx.x;
  if (t >= NN * NG) return;
  int n = t / NG;
  int g = t - n * NG;
  int r0 = rowptr[n], r1 = rowptr[n + 1];
  float ax = 0.f, ay = 0.f, az = 0.f, aww = 0.f;
  const float* hb = h + (size_t)g * 4;
  for (int p = r0; p < r1; ++p) {
    float al = aw[p];
    int s = srcs[p];
    float4 hv = *reinterpret_cast<const float4*>(hb + (size_t)s * HP);
    ax += al * hv.x;
    ay += al * hv.y;
    az += al * hv.z;
    aww += al * hv.w;
  }
  float4 bv = *reinterpret_cast<const float4*>(biasp + g * 4);
  float4 r;
  r.x = ax + bv.x; r.y = ay + bv.y; r.z = az + bv.z; r.w = aww + bv.w;
  if (RELU) {
    r.x = fmaxf(r.x, 0.f); r.y = fmaxf(r.y, 0.f);
    r.z = fmaxf(r.z, 0.f); r.w = fmaxf(r.w, 0.f);
  }
  *reinterpret_cast<float4*>(outp + (size_t)n * HP + g * 4) = r;
}

__global__ void prep_bias(const float* __restrict__ b1, const float* __restrict__ b2,
                          float* __restrict__ b1p, float* __restrict__ b2p) {
  int t = threadIdx.x;
  if (t < HP) {
    b1p[t] = (t < H) ? b1[t] : 0.f;
    b2p[t] = (t < H) ? b2[t] : 0.f;
  }
}

__global__ void final_node(const float* __restrict__ h2f, const float* __restrict__ Wf,
                           float* __restrict__ u, float* __restrict__ v) {
  int n = blockIdx.x * blockDim.x + threadIdx.x;
  if (n >= NN) return;
  const float* r = h2f + (size_t)n * HP;
  float su = 0.f, sv = 0.f;
#pragma unroll
  for (int j = 0; j < H; ++j) {
    float hv = r[j];
    su += hv * Wf[j];
    sv += hv * Wf[H + j];
  }
  u[n] = su;
  v[n] = sv;
}

__global__ void transpose_wm1(const float* __restrict__ Wm1, float* __restrict__ wm1t) {
  int t = blockIdx.x * blockDim.x + threadIdx.x;
  if (t >= FE * H) return;
  int k = t / H, j = t % H;
  wm1t[j * FE + k] = Wm1[t];
}

__global__ void mk_wproj(const float* __restrict__ Wm2, const float* __restrict__ bm2,
                         const float* __restrict__ Wf, const float* __restrict__ bf,
                         float* __restrict__ wpc) {
  int k = threadIdx.x;
  if (k < H) {
    float s = 0.f;
    for (int j = 0; j < H; ++j) s += Wm2[k * H + j] * Wf[2 * H + j];
    wpc[k] = s;
  } else if (k == H) {
    float s = 0.f;
    for (int j = 0; j < H; ++j) s += bm2[j] * Wf[2 * H + j];
    wpc[H] = s + bf[0];
  }
}

// ---------------- edge head: weights staged in LDS, ea row in registers --------------
__device__ __forceinline__ float dot4(float4 a, float4 b, float c) {
  return fmaf(a.x, b.x, fmaf(a.y, b.y, fmaf(a.z, b.z, fmaf(a.w, b.w, c))));
}

__global__ __launch_bounds__(256)
void final_edge(const int* __restrict__ ei, const float* __restrict__ ea,
                const float* __restrict__ wm1t, const float* __restrict__ bm1,
                const float* __restrict__ wpc, const float* __restrict__ u,
                const float* __restrict__ v, float* __restrict__ out) {
  __shared__ float4 wsh[H * FE4];   // 78*8 float4 = 9984 B, row j at wsh[j*8..]
  __shared__ float bsh[H];          // bm1
  __shared__ float csh[H];          // wpc[0:H]
  int t = threadIdx.x;
  const float4* wg = reinterpret_cast<const float4*>(wm1t);
  for (int i = t; i < H * FE4; i += 256) wsh[i] = wg[i];
  if (t < H) { bsh[t] = bm1[t]; csh[t] = wpc[t]; }
  __syncthreads();

  int e = blockIdx.x * 256 + t;
  if (e >= NE) return;
  const float4* eap = reinterpret_cast<const float4*>(ea + (size_t)e * FE);
  float4 a0 = eap[0], a1 = eap[1], a2 = eap[2], a3 = eap[3];
  float4 a4 = eap[4], a5 = eap[5], a6 = eap[6], a7 = eap[7];
  int s = ei[e], d = ei[NE + e];
  float r = u[s] + v[d] + wpc[H];
#pragma unroll 2
  for (int j = 0; j < H; ++j) {
    const float4* wr = wsh + j * FE4;
    float t0 = dot4(a0, wr[0], dot4(a4, wr[4], bsh[j]));
    float t1 = dot4(a1, wr[1], dot4(a5, wr[5], 0.f));
    float t2 = dot4(a2, wr[2], dot4(a6, wr[6], 0.f));
    float t3 = dot4(a3, wr[3], dot4(a7, wr[7], 0.f));
    float tt = (t0 + t1) + (t2 + t3);
    r = fmaf(fmaxf(tt, 0.f), csh[j], r);
  }
  out[e] = r;
}

extern "C" void kernel_launch(void* const* d_in, const int* in_sizes, int n_in,
                              void* d_out, int out_size, void* d_ws, size_t ws_size,
                              hipStream_t stream) {
  const float* x   = (const float*)d_in[0];
  const int*   ei  = (const int*)d_in[1];
  const float* ea  = (const float*)d_in[2];
  const float* W1  = (const float*)d_in[3];
  const float* as1 = (const float*)d_in[4];
  const float* ad1 = (const float*)d_in[5];
  const float* b1  = (const float*)d_in[6];
  const float* W2  = (const float*)d_in[7];
  const float* as2 = (const float*)d_in[8];
  const float* ad2 = (const float*)d_in[9];
  const float* b2  = (const float*)d_in[10];
  const float* Wm1 = (const float*)d_in[11];
  const float* bm1 = (const float*)d_in[12];
  const float* Wm2 = (const float*)d_in[13];
  const float* bm2 = (const float*)d_in[14];
  const float* Wf  = (const float*)d_in[15];
  const float* bf  = (const float*)d_in[16];
  float* out = (float*)d_out;

  float* w = (float*)d_ws;
  float* h1   = w; w += (size_t)NN * HP;   // layer1 h; later reused as layer2 agg out
  float* bufB = w; w += (size_t)NN * HP;   // layer1 agg out (h1r) = layer2 gemm input
  float* h2   = w; w += (size_t)NN * HP;
  float* asv  = w; w += NN;
  float* adv  = w; w += NN;
  float* uu   = w; w += NN;
  float* vv   = w; w += NN;
  float* wpc  = w; w += HP;
  float* wm1t = w; w += H * FE;
  float* b1p  = w; w += HP;
  float* b2p  = w; w += HP;
  float* aw   = w; w += ETOT;
  int* deg    = (int*)w; w += NN;
  int* rowptr = (int*)w; w += NN + 1;
  int* cursor = (int*)w; w += NN;
  int* srcs   = (int*)w; w += ETOT;
  int* bsum   = (int*)w; w += NBLK;
  int* boff   = (int*)w; w += NBLK;

  const int B = 256;
  dim3 gN((NN + B - 1) / B);
  dim3 gE((ETOT + B - 1) / B);
  dim3 gA((NN * NG + B - 1) / B);
  dim3 gEo((NE + B - 1) / B);

  // ---- CSR build (dst-sorted) ----
  zero_deg<<<gN, B, 0, stream>>>(deg);
  deg_count<<<gE, B, 0, stream>>>(ei, deg);
  scan1<<<NBLK, SCAN_B, 0, stream>>>(deg, bsum);
  scan2<<<1, 64, 0, stream>>>(bsum, boff);
  scan3<<<NBLK, SCAN_B, 0, stream>>>(deg, boff, rowptr, cursor);
  csr_fill<<<gE, B, 0, stream>>>(ei, cursor, srcs);
  prep_bias<<<1, 128, 0, stream>>>(b1, b2, b1p, b2p);

  // ---- layer 1 ----
  gemm_node<FIN, FIN><<<gN, B, 0, stream>>>(x, W1, as1, ad1, h1, asv, adv);
  softmax_csr<<<gN, B, 0, stream>>>(rowptr, srcs, asv, adv, aw);
  agg_csr<1><<<gA, B, 0, stream>>>(rowptr, srcs, aw, h1, b1p, bufB);

  // ---- layer 2 ----
  gemm_node<H, HP><<<gN, B, 0, stream>>>(bufB, W2, as2, ad2, h2, asv, adv);
  softmax_csr<<<gN, B, 0, stream>>>(rowptr, srcs, asv, adv, aw);
  agg_csr<0><<<gA, B, 0, stream>>>(rowptr, srcs, aw, h2, b2p, h1);
  final_node<<<gN, B, 0, stream>>>(h1, Wf, uu, vv);

  // ---- edge head ----
  transpose_wm1<<<(FE * H + B - 1) / B, B, 0, stream>>>(Wm1, wm1t);
  mk_wproj<<<1, 128, 0, stream>>>(Wm2, bm2, Wf, bf, wpc);
  final_edge<<<gEo, B, 0, stream>>>(ei, ea, wm1t, bm1, wpc, uu, vv, out);
}

// Round 6
// 564.963 us; speedup vs baseline: 1.0452x; 1.0452x over previous
//
#include <hip/hip_runtime.h>
#include <math.h>

#define NN 50000
#define NE 1200000
#define FIN 128
#define FE 32
#define H 78
#define HP 80
#define ETOT (NE + NN)
#define NG (HP / 4)          // 20 float4 groups per node row

#define SCAN_B 256
#define SCAN_C 4
#define SCAN_TILE (SCAN_B * SCAN_C)                 // 1024
#define NBLK ((NN + SCAN_TILE - 1) / SCAN_TILE)     // 49

// ---------------- dense node GEMM with fused attention-score epilogue ----------------
template<int K, int LDA>
__global__ void gemm_node(const float* __restrict__ A, const float* __restrict__ W,
                          const float* __restrict__ as, const float* __restrict__ ad,
                          float* __restrict__ C, float* __restrict__ asv,
                          float* __restrict__ adv) {
  int n = blockIdx.x * blockDim.x + threadIdx.x;
  if (n >= NN) return;
  const float* a = A + (size_t)n * LDA;
  float acc[H];
#pragma unroll
  for (int j = 0; j < H; ++j) acc[j] = 0.f;
  int k = 0;
  for (; k + 4 <= K; k += 4) {
    float4 av = *reinterpret_cast<const float4*>(a + k);
    const float* w0 = W + (size_t)k * H;
#pragma unroll
    for (int j = 0; j < H; ++j) acc[j] += av.x * w0[j];
#pragma unroll
    for (int j = 0; j < H; ++j) acc[j] += av.y * w0[H + j];
#pragma unroll
    for (int j = 0; j < H; ++j) acc[j] += av.z * w0[2 * H + j];
#pragma unroll
    for (int j = 0; j < H; ++j) acc[j] += av.w * w0[3 * H + j];
  }
  for (; k < K; ++k) {
    float av = a[k];
    const float* w0 = W + (size_t)k * H;
#pragma unroll
    for (int j = 0; j < H; ++j) acc[j] += av * w0[j];
  }
  float* c = C + (size_t)n * HP;
#pragma unroll
  for (int j = 0; j < H; ++j) c[j] = acc[j];
  c[H] = 0.f;
  c[H + 1] = 0.f;
  float sa = 0.f, sd = 0.f;
#pragma unroll
  for (int j = 0; j < H; ++j) {
    sa += acc[j] * as[j];
    sd += acc[j] * ad[j];
  }
  asv[n] = sa;
  adv[n] = sd;
}

// ---------------- CSR build ----------------
__global__ void zero_deg(int* __restrict__ deg) {
  int n = blockIdx.x * blockDim.x + threadIdx.x;
  if (n < NN) deg[n] = 0;
}

__global__ void deg_count(const int* __restrict__ ei, int* __restrict__ deg) {
  int i = blockIdx.x * blockDim.x + threadIdx.x;
  if (i >= ETOT) return;
  int dst = (i < NE) ? ei[NE + i] : (i - NE);
  atomicAdd(deg + dst, 1);
}

__global__ void scan1(const int* __restrict__ deg, int* __restrict__ bsum) {
  __shared__ int sh[SCAN_B];
  int b = blockIdx.x, t = threadIdx.x;
  int base = b * SCAN_TILE + t * SCAN_C;
  int s = 0;
#pragma unroll
  for (int k = 0; k < SCAN_C; ++k) {
    int i = base + k;
    if (i < NN) s += deg[i];
  }
  sh[t] = s;
  __syncthreads();
  for (int off = SCAN_B / 2; off > 0; off >>= 1) {
    if (t < off) sh[t] += sh[t + off];
    __syncthreads();
  }
  if (t == 0) bsum[b] = sh[0];
}

__global__ void scan2(const int* __restrict__ bsum, int* __restrict__ boff) {
  __shared__ int sh[64];
  int t = threadIdx.x;
  sh[t] = (t < NBLK) ? bsum[t] : 0;
  __syncthreads();
  for (int off = 1; off < 64; off <<= 1) {
    int v = (t >= off) ? sh[t - off] : 0;
    __syncthreads();
    sh[t] += v;
    __syncthreads();
  }
  if (t < NBLK) boff[t] = (t == 0) ? 0 : sh[t - 1];
}

__global__ void scan3(const int* __restrict__ deg, const int* __restrict__ boff,
                      int* __restrict__ rowptr, int* __restrict__ cursor) {
  __shared__ int sh[SCAN_B];
  int b = blockIdx.x, t = threadIdx.x;
  int base = b * SCAN_TILE + t * SCAN_C;
  int v[SCAN_C];
  int s = 0;
#pragma unroll
  for (int k = 0; k < SCAN_C; ++k) {
    int i = base + k;
    v[k] = (i < NN) ? deg[i] : 0;
    s += v[k];
  }
  sh[t] = s;
  __syncthreads();
  for (int off = 1; off < SCAN_B; off <<= 1) {
    int u = (t >= off) ? sh[t - off] : 0;
    __syncthreads();
    sh[t] += u;
    __syncthreads();
  }
  int run = boff[b] + ((t == 0) ? 0 : sh[t - 1]);
#pragma unroll
  for (int k = 0; k < SCAN_C; ++k) {
    int i = base + k;
    if (i < NN) {
      rowptr[i] = run;
      cursor[i] = run;
      run += v[k];
    }
  }
  if (b == 0 && t == 0) rowptr[NN] = ETOT;
}

__global__ void csr_fill(const int* __restrict__ ei, int* __restrict__ cursor,
                         int* __restrict__ srcs) {
  int i = blockIdx.x * blockDim.x + threadIdx.x;
  if (i >= ETOT) return;
  int src, dst;
  if (i < NE) { src = ei[i]; dst = ei[NE + i]; }
  else { src = dst = i - NE; }
  int pos = atomicAdd(cursor + dst, 1);
  srcs[pos] = src;
}

// ---------------- per-destination ONLINE softmax (1 random-gather pass) ----------------
__global__ void softmax_csr(const int* __restrict__ rowptr, const int* __restrict__ srcs,
                            const float* __restrict__ asv, const float* __restrict__ adv,
                            float* __restrict__ aw) {
  int n = blockIdx.x * blockDim.x + threadIdx.x;
  if (n >= NN) return;
  int r0 = rowptr[n], r1 = rowptr[n + 1];
  float advn = adv[n];
  float m = -INFINITY, s = 0.f;
  for (int p = r0; p < r1; ++p) {
    float e = asv[srcs[p]] + advn;
    e = e > 0.f ? e : 0.2f * e;
    aw[p] = e;
    if (e > m) {
      s = s * __expf(m - e);   // exp(-inf)=0 handles first iteration
      m = e;
    }
    s += __expf(e - m);
  }
  float inv = 1.f / (s + 1e-16f);
  for (int p = r0; p < r1; ++p) aw[p] = __expf(aw[p] - m) * inv;
}

// ---------------- gather-based aggregation; bias (+optional relu) fused ----------------
template<int RELU>
__global__ void agg_csr(const int* __restrict__ rowptr, const int* __restrict__ srcs,
                        const float* __restrict__ aw, const float* __restrict__ h,
                        const float* __restrict__ biasp, float* __restrict__ outp) {
  int t = blockIdx.x * blockDim.x + threadIdx.x;
  if (t >= NN * NG) return;
  int n = t / NG;
  int g = t - n * NG;
  int r0 = rowptr[n], r1 = rowptr[n + 1];
  float ax = 0.f, ay = 0.f, az = 0.f, aww = 0.f;
  const float* hb = h + (size_t)g * 4;
  for (int p = r0; p < r1; ++p) {
    float al = aw[p];
    int s = srcs[p];
    float4 hv = *reinterpret_cast<const float4*>(hb + (size_t)s * HP);
    ax += al * hv.x;
    ay += al * hv.y;
    az += al * hv.z;
    aww += al * hv.w;
  }
  float4 bv = *reinterpret_cast<const float4*>(biasp + g * 4);
  float4 r;
  r.x = ax + bv.x; r.y = ay + bv.y; r.z = az + bv.z; r.w = aww + bv.w;
  if (RELU) {
    r.x = fmaxf(r.x, 0.f); r.y = fmaxf(r.y, 0.f);
    r.z = fmaxf(r.z, 0.f); r.w = fmaxf(r.w, 0.f);
  }
  *reinterpret_cast<float4*>(outp + (size_t)n * HP + g * 4) = r;
}

__global__ void prep_bias(const float* __restrict__ b1, const float* __restrict__ b2,
                          float* __restrict__ b1p, float* __restrict__ b2p) {
  int t = threadIdx.x;
  if (t < HP) {
    b1p[t] = (t < H) ? b1[t] : 0.f;
    b2p[t] = (t < H) ? b2[t] : 0.f;
  }
}

__global__ void final_node(const float* __restrict__ h2f, const float* __restrict__ Wf,
                           float* __restrict__ u, float* __restrict__ v) {
  int n = blockIdx.x * blockDim.x + threadIdx.x;
  if (n >= NN) return;
  const float* r = h2f + (size_t)n * HP;
  float su = 0.f, sv = 0.f;
#pragma unroll
  for (int j = 0; j < H; ++j) {
    float hv = r[j];
    su += hv * Wf[j];
    sv += hv * Wf[H + j];
  }
  u[n] = su;
  v[n] = sv;
}

__global__ void mk_wproj(const float* __restrict__ Wm2, const float* __restrict__ bm2,
                         const float* __restrict__ Wf, const float* __restrict__ bf,
                         float* __restrict__ wpc) {
  int k = threadIdx.x;
  if (k < H) {
    float s = 0.f;
    for (int j = 0; j < H; ++j) s += Wm2[k * H + j] * Wf[2 * H + j];
    wpc[k] = s;
  } else if (k == H) {
    float s = 0.f;
    for (int j = 0; j < H; ++j) s += bm2[j] * Wf[2 * H + j];
    wpc[H] = s + bf[0];
  }
}

// ---------------- edge head: gemm_node-style accumulator form --------------
// acc[78] forces registers live; Wm1 is already [FE][H] row-major (the layout we want).
// out[e] = u[src] + v[dst] + wpc[H] + sum_j relu(acc[j] + bm1[j]) * wpc[j]
__global__ void final_edge(const int* __restrict__ ei, const float* __restrict__ ea,
                           const float* __restrict__ Wm1, const float* __restrict__ bm1,
                           const float* __restrict__ wpc, const float* __restrict__ u,
                           const float* __restrict__ v, float* __restrict__ out) {
  int e = blockIdx.x * blockDim.x + threadIdx.x;
  if (e >= NE) return;
  const float* a = ea + (size_t)e * FE;
  float acc[H];
#pragma unroll
  for (int j = 0; j < H; ++j) acc[j] = 0.f;
#pragma unroll
  for (int k = 0; k < FE; k += 4) {
    float4 av = *reinterpret_cast<const float4*>(a + k);
    const float* w0 = Wm1 + (size_t)k * H;
#pragma unroll
    for (int j = 0; j < H; ++j) acc[j] += av.x * w0[j];
#pragma unroll
    for (int j = 0; j < H; ++j) acc[j] += av.y * w0[H + j];
#pragma unroll
    for (int j = 0; j < H; ++j) acc[j] += av.z * w0[2 * H + j];
#pragma unroll
    for (int j = 0; j < H; ++j) acc[j] += av.w * w0[3 * H + j];
  }
  int s = ei[e], d = ei[NE + e];
  float r = u[s] + v[d] + wpc[H];
#pragma unroll
  for (int j = 0; j < H; ++j)
    r = fmaf(fmaxf(acc[j] + bm1[j], 0.f), wpc[j], r);
  out[e] = r;
}

extern "C" void kernel_launch(void* const* d_in, const int* in_sizes, int n_in,
                              void* d_out, int out_size, void* d_ws, size_t ws_size,
                              hipStream_t stream) {
  const float* x   = (const float*)d_in[0];
  const int*   ei  = (const int*)d_in[1];
  const float* ea  = (const float*)d_in[2];
  const float* W1  = (const float*)d_in[3];
  const float* as1 = (const float*)d_in[4];
  const float* ad1 = (const float*)d_in[5];
  const float* b1  = (const float*)d_in[6];
  const float* W2  = (const float*)d_in[7];
  const float* as2 = (const float*)d_in[8];
  const float* ad2 = (const float*)d_in[9];
  const float* b2  = (const float*)d_in[10];
  const float* Wm1 = (const float*)d_in[11];
  const float* bm1 = (const float*)d_in[12];
  const float* Wm2 = (const float*)d_in[13];
  const float* bm2 = (const float*)d_in[14];
  const float* Wf  = (const float*)d_in[15];
  const float* bf  = (const float*)d_in[16];
  float* out = (float*)d_out;

  float* w = (float*)d_ws;
  float* h1   = w; w += (size_t)NN * HP;   // layer1 h; later reused as layer2 agg out
  float* bufB = w; w += (size_t)NN * HP;   // layer1 agg out (h1r) = layer2 gemm input
  float* h2   = w; w += (size_t)NN * HP;
  float* asv  = w; w += NN;
  float* adv  = w; w += NN;
  float* uu   = w; w += NN;
  float* vv   = w; w += NN;
  float* wpc  = w; w += HP;
  float* b1p  = w; w += HP;
  float* b2p  = w; w += HP;
  float* aw   = w; w += ETOT;
  int* deg    = (int*)w; w += NN;
  int* rowptr = (int*)w; w += NN + 1;
  int* cursor = (int*)w; w += NN;
  int* srcs   = (int*)w; w += ETOT;
  int* bsum   = (int*)w; w += NBLK;
  int* boff   = (int*)w; w += NBLK;

  const int B = 256;
  dim3 gN((NN + B - 1) / B);
  dim3 gE((ETOT + B - 1) / B);
  dim3 gA((NN * NG + B - 1) / B);
  dim3 gEo((NE + B - 1) / B);

  // ---- CSR build (dst-sorted) ----
  zero_deg<<<gN, B, 0, stream>>>(deg);
  deg_count<<<gE, B, 0, stream>>>(ei, deg);
  scan1<<<NBLK, SCAN_B, 0, stream>>>(deg, bsum);
  scan2<<<1, 64, 0, stream>>>(bsum, boff);
  scan3<<<NBLK, SCAN_B, 0, stream>>>(deg, boff, rowptr, cursor);
  csr_fill<<<gE, B, 0, stream>>>(ei, cursor, srcs);
  prep_bias<<<1, 128, 0, stream>>>(b1, b2, b1p, b2p);

  // ---- layer 1 ----
  gemm_node<FIN, FIN><<<gN, B, 0, stream>>>(x, W1, as1, ad1, h1, asv, adv);
  softmax_csr<<<gN, B, 0, stream>>>(rowptr, srcs, asv, adv, aw);
  agg_csr<1><<<gA, B, 0, stream>>>(rowptr, srcs, aw, h1, b1p, bufB);

  // ---- layer 2 ----
  gemm_node<H, HP><<<gN, B, 0, stream>>>(bufB, W2, as2, ad2, h2, asv, adv);
  softmax_csr<<<gN, B, 0, stream>>>(rowptr, srcs, asv, adv, aw);
  agg_csr<0><<<gA, B, 0, stream>>>(rowptr, srcs, aw, h2, b2p, h1);
  final_node<<<gN, B, 0, stream>>>(h1, Wf, uu, vv);

  // ---- edge head ----
  mk_wproj<<<1, 128, 0, stream>>>(Wm2, bm2, Wf, bf, wpc);
  final_edge<<<gEo, B, 0, stream>>>(ei, ea, Wm1, bm1, wpc, uu, vv, out);
}